// Round 19
// baseline (135.511 us; speedup 1.0000x reference)
//
#include <hip/hip_runtime.h>
#include <hip/hip_bf16.h>

#define EMBED 1024
#define HEADS 16
#define HDIM  64
#define BATCH 2
#define SEQ   2048
#define MTOT  (BATCH*SEQ)   // 4096

typedef __attribute__((ext_vector_type(8))) short bf16x8;
typedef __attribute__((ext_vector_type(4))) short bf16x4;
typedef __attribute__((ext_vector_type(4))) float f32x4;
typedef __attribute__((ext_vector_type(8))) unsigned short u16x8;
typedef __attribute__((ext_vector_type(2))) unsigned u32x2;
typedef __attribute__((ext_vector_type(4))) unsigned u32x4;

// native RNE f32->bf16 pair: compiles to one v_cvt_pk_bf16_f32
__device__ __forceinline__ unsigned pack2(float lo, float hi) {
    __hip_bfloat162 h = __float22bfloat162_rn(make_float2(lo, hi));
    unsigned u;
    __builtin_memcpy(&u, &h, sizeof(u));
    return u;
}
__device__ __forceinline__ unsigned short f2bf(float f) {
    __hip_bfloat16 h = __float2bfloat16(f);
    unsigned short u;
    __builtin_memcpy(&u, &h, sizeof(u));
    return u;
}

// async global->LDS DMA, 16B per lane (dest = lds base + lane*16)
__device__ __forceinline__ void glds16(const void* g, void* l) {
    __builtin_amdgcn_global_load_lds(
        (const __attribute__((address_space(1))) void*)g,
        (__attribute__((address_space(3))) void*)l, 16, 0, 0);
}

// ------------------------------------------------------------------
// Kernel 0: one-shot f32 -> bf16 conversion (unchanged).
// ------------------------------------------------------------------
__global__ __launch_bounds__(256) void preconvert(
    const float* __restrict__ x,
    const float* __restrict__ wq, const float* __restrict__ wk,
    const float* __restrict__ wv, const float* __restrict__ wo,
    unsigned short* __restrict__ xb,
    unsigned short* __restrict__ wqb, unsigned short* __restrict__ wkb,
    unsigned short* __restrict__ wvb, unsigned short* __restrict__ wob)
{
    const int NX = (MTOT * EMBED) / 4;
    const int NW = (EMBED * EMBED) / 4;
    int idx = blockIdx.x * 256 + threadIdx.x;
    const float* src;
    unsigned short* dst;
    int off;
    if (idx < NX) {
        src = x; dst = xb; off = idx;
    } else {
        int r = idx - NX;
        int w = r / NW;
        off = r - w * NW;
        src = (w == 0) ? wq : (w == 1) ? wk : (w == 2) ? wv : wo;
        dst = (w == 0) ? wqb : (w == 1) ? wkb : (w == 2) ? wvb : wob;
    }
    float4 v = ((const float4*)src)[off];
    u32x2 o;
    o[0] = pack2(v.x, v.y);
    o[1] = pack2(v.z, v.w);
    *(u32x2*)(dst + (size_t)off * 4) = o;
}

// ------------------------------------------------------------------
// Kernel 1: QKV projection (m97 glds staging; K pre-scaled by
// 0.125*log2e so attention scores come out in exp2 units).
// ------------------------------------------------------------------
__global__ __launch_bounds__(256, 2) void qkv_proj(
    const unsigned short* __restrict__ xb,
    const unsigned short* __restrict__ wqb, const float* __restrict__ bq,
    const unsigned short* __restrict__ wkb, const float* __restrict__ bk,
    const unsigned short* __restrict__ wvb, const float* __restrict__ bv,
    unsigned short* __restrict__ qo,
    unsigned short* __restrict__ ko,
    unsigned short* __restrict__ vto)
{
    const int which = blockIdx.z;
    const unsigned short* __restrict__ w =
        (which == 0) ? wqb : (which == 1) ? wkb : wvb;
    const float* __restrict__ bias = (which == 0) ? bq : (which == 1) ? bk : bv;
    const float kscale = (which == 1) ? 0.18033688f : 1.0f;  // 0.125*log2e

    const int m0 = blockIdx.x * 128;
    const int n0 = blockIdx.y * 128;

    __shared__ __align__(16) unsigned short a_lds[128 * 32];
    __shared__ __align__(16) unsigned short b_lds[128 * 32];

    const int tid  = threadIdx.x;
    const int lane = tid & 63;
    const int wid  = tid >> 6;
    const int wr   = wid >> 1, wc = wid & 1;
    const int lq   = lane & 15;
    const int lg   = lane >> 4;

    f32x4 acc[4][4] = {};

    const int srow  = wid * 32 + (lane >> 2);
    const int scol8 = (lane & 3) * 8;
    const unsigned short* ap0 = xb + (size_t)(m0 + srow)      * EMBED + scol8;
    const unsigned short* ap1 = xb + (size_t)(m0 + srow + 16) * EMBED + scol8;
    const unsigned short* bp0 = w  + (size_t)(n0 + srow)      * EMBED + scol8;
    const unsigned short* bp1 = w  + (size_t)(n0 + srow + 16) * EMBED + scol8;
    unsigned short* la0 = a_lds + wid * 1024;
    unsigned short* la1 = a_lds + wid * 1024 + 512;
    unsigned short* lb0 = b_lds + wid * 1024;
    unsigned short* lb1 = b_lds + wid * 1024 + 512;

    for (int k0 = 0; k0 < EMBED; k0 += 32) {
        glds16(ap0 + k0, la0);
        glds16(ap1 + k0, la1);
        glds16(bp0 + k0, lb0);
        glds16(bp1 + k0, lb1);
        __syncthreads();
        bf16x8 af[4], bfr[4];
        #pragma unroll
        for (int i = 0; i < 4; ++i)
            af[i] = *(const bf16x8*)&a_lds[(wr*64 + i*16 + lq) * 32 + lg*8];
        #pragma unroll
        for (int j = 0; j < 4; ++j)
            bfr[j] = *(const bf16x8*)&b_lds[(wc*64 + j*16 + lq) * 32 + lg*8];
        #pragma unroll
        for (int i = 0; i < 4; ++i)
            #pragma unroll
            for (int j = 0; j < 4; ++j)
                acc[i][j] = __builtin_amdgcn_mfma_f32_16x16x32_bf16(af[i], bfr[j], acc[i][j], 0, 0, 0);
        __syncthreads();
    }

    #pragma unroll
    for (int j = 0; j < 4; ++j) {
        const int nn = n0 + wc*64 + j*16 + lq;
        const float bsv = bias[nn];
        const int h = nn >> 6, d = nn & (HDIM-1);
        #pragma unroll
        for (int i = 0; i < 4; ++i) {
            const int mmb = m0 + wr*64 + i*16 + lg*4;
            const int b = mmb >> 11;
            const int s = mmb & (SEQ-1);
            const size_t bh = (size_t)(b*HEADS + h);
            if (which == 2) {
                u32x2 ov;
                ov[0] = pack2(acc[i][j][0] + bsv, acc[i][j][1] + bsv);
                ov[1] = pack2(acc[i][j][2] + bsv, acc[i][j][3] + bsv);
                *(u32x2*)&vto[(bh*HDIM + d)*SEQ + s] = ov;
            } else {
                unsigned short* o = (which == 0) ? qo : ko;
                #pragma unroll
                for (int r = 0; r < 4; ++r)
                    o[(bh*SEQ + (s + r))*HDIM + d] = f2bf((acc[i][j][r] + bsv) * kscale);
            }
        }
    }
}

// ------------------------------------------------------------------
// Kernel 2: flash attention v14 — R13 geometry (1024 blocks, 4 waves,
// 16 q-rows/wave -> 16 waves/CU) + the two orthogonal improvements
// proven on the R14 shape:
//   - ones-MFMA l-accum (replaces psum VALU adds + final shfl reduce)
//   - T5 s_setprio(1) around the PV MFMA cluster (+4.3us measured on
//     R18; more cross-block phase diversity here should help >= that)
// Core: K-row-permuted QK^T, K=32 PV with lane-local P, zero-conflict
// row-hash LDS, no online max, dbuf + T14 pipeline, XCD swizzle.
// ------------------------------------------------------------------
__global__ __launch_bounds__(256, 4) void attn(
    const unsigned short* __restrict__ q,
    const unsigned short* __restrict__ k,
    const unsigned short* __restrict__ vt,
    unsigned short* __restrict__ ctx)
{
    __shared__ __align__(16) unsigned char sm[2 * 16384];  // per buf: K 8KB, V 8KB

    const int bid   = blockIdx.x;          // 0..1023
    const int xcd   = bid & 7;
    const int local = bid >> 3;            // 0..127
    const int bh    = xcd * 4 + (local >> 5);
    const int q0    = (local & 31) * 64;   // 64 q-rows per block
    const int b     = bh >> 4;
    const int h     = bh & (HEADS - 1);
    const int tid   = threadIdx.x;
    const int wv    = tid >> 6;
    const int lane  = tid & 63;
    const int lq = lane & 15, lg = lane >> 4;

    const unsigned short* qb = q  + (size_t)bh * SEQ * HDIM;
    const unsigned short* kb = k  + (size_t)bh * SEQ * HDIM;
    const unsigned short* vb = vt + (size_t)bh * HDIM * SEQ;

    // K-read offsets: row perm(sub,lq) with lane-constant swizzle
    const int lg16 = lg * 16;
    const int Sp = (((lq & 3) | (((lq >> 2) & 1) << 2)) << 4);
    const int Tp = (((lq & 3) | (((lq >> 3) & 1) << 2)) << 4);
    const int kreadA = (8*(lq >> 2) + (lq & 3)) * 128 + (lg16 ^ Sp);  // d 0-31
    const int kreadB = kreadA ^ 64;                                    // d 32-63
    const int vreadA = lq * 128 + (lg16 ^ Tp);   // + i*2048, kv 0-31
    const int vreadB = vreadA ^ 64;              //            kv 32-63

    // staging offsets (identical for K and V tiles)
    const int wrow = tid >> 3;             // 0..31
    const int c8   = tid & 7;              // 0..7
    const int wS   = (((wrow & 3) | (((wrow >> 3) & 1) << 2)) << 4);
    const int woff = wrow * 128 + ((c8 * 16) ^ wS);

    const int scol = c8 * 8;
    const unsigned short* kp = kb + (size_t)wrow * HDIM + scol;
    const unsigned short* vp = vb + (size_t)wrow * SEQ + scol;

    // this wave's 16 q-rows (single q-frag)
    bf16x8 qf[2];
    #pragma unroll
    for (int hh = 0; hh < 2; ++hh)
        qf[hh] = *(const bf16x8*)(qb + (size_t)(q0 + wv*16 + lq) * HDIM + hh*32 + lg*8);

    // ones fragment (bf16 1.0 = 0x3F80) for the P-sum MFMA
    u16x8 ones_u;
    #pragma unroll
    for (int e = 0; e < 8; ++e) ones_u[e] = 0x3F80;
    const bf16x8 ones = __builtin_bit_cast(bf16x8, ones_u);

    f32x4 o[4] = {};
    f32x4 acc_l = {};

    u16x8 kr0, kr1, vr0, vr1;

#define LOADT() do {                                                           \
    kr0 = *(const u16x8*)(kp);                                                 \
    kr1 = *(const u16x8*)(kp + 32*HDIM);                                       \
    vr0 = *(const u16x8*)(vp);                                                 \
    vr1 = *(const u16x8*)(vp + 32*SEQ);                                        \
} while (0)

#define WRITET(BF) do {                                                        \
    unsigned char* smb = sm + (BF)*16384;                                      \
    *(u16x8*)(smb +         woff) = kr0;                                       \
    *(u16x8*)(smb +  4096 + woff) = kr1;                                       \
    *(u16x8*)(smb +  8192 + woff) = vr0;                                       \
    *(u16x8*)(smb + 12288 + woff) = vr1;                                       \
} while (0)

#define COMPUTE(BF) do {                                                       \
    const unsigned char* smb = sm + (BF)*16384;                                \
    f32x4 s_[4];                                                               \
    _Pragma("unroll")                                                          \
    for (int sub = 0; sub < 4; ++sub) {                                        \
        const int sadd = (sub & 1) * 512 + (sub >> 1) * 4096;                  \
        bf16x8 k0 = *(const bf16x8*)(smb + sadd + kreadA);                     \
        bf16x8 k1 = *(const bf16x8*)(smb + sadd + kreadB);                     \
        f32x4 z = {};                                                          \
        z = __builtin_amdgcn_mfma_f32_16x16x32_bf16(k0, qf[0], z, 0, 0, 0);    \
        z = __builtin_amdgcn_mfma_f32_16x16x32_bf16(k1, qf[1], z, 0, 0, 0);    \
        s_[sub] = z;                                                           \
    }                                                                          \
    u32x4 pw0, pw1;                                                            \
    _Pragma("unroll")                                                          \
    for (int sub = 0; sub < 4; ++sub) {                                        \
        f32x4 pv;                                                              \
        _Pragma("unroll")                                                      \
        for (int r = 0; r < 4; ++r) pv[r] = exp2f(s_[sub][r]);                 \
        unsigned d0 = pack2(pv[0], pv[1]);                                     \
        unsigned d1 = pack2(pv[2], pv[3]);                                     \
        if (sub == 0)      { pw0[0] = d0; pw0[1] = d1; }                       \
        else if (sub == 1) { pw0[2] = d0; pw0[3] = d1; }                       \
        else if (sub == 2) { pw1[0] = d0; pw1[1] = d1; }                       \
        else               { pw1[2] = d0; pw1[3] = d1; }                       \
    }                                                                          \
    bf16x8 pb0 = __builtin_bit_cast(bf16x8, pw0);                              \
    bf16x8 pb1 = __builtin_bit_cast(bf16x8, pw1);                              \
    acc_l = __builtin_amdgcn_mfma_f32_16x16x32_bf16(ones, pb0, acc_l, 0, 0, 0);\
    acc_l = __builtin_amdgcn_mfma_f32_16x16x32_bf16(ones, pb1, acc_l, 0, 0, 0);\
    __builtin_amdgcn_s_setprio(1);                                             \
    _Pragma("unroll")                                                          \
    for (int i = 0; i < 4; ++i) {                                              \
        bf16x8 va  = *(const bf16x8*)(smb + 8192 + i*2048 + vreadA);           \
        bf16x8 vbq = *(const bf16x8*)(smb + 8192 + i*2048 + vreadB);           \
        o[i] = __builtin_amdgcn_mfma_f32_16x16x32_bf16(va,  pb0, o[i], 0, 0, 0); \
        o[i] = __builtin_amdgcn_mfma_f32_16x16x32_bf16(vbq, pb1, o[i], 0, 0, 0); \
    }                                                                          \
    __builtin_amdgcn_s_setprio(0);                                             \
} while (0)

    LOADT();
    WRITET(0);
    __syncthreads();
    kp += 64 * HDIM;
    vp += 64;

    for (int t2 = 0; t2 < 16; ++t2) {
        {
            const int t = 2 * t2;
            if (t < 31) LOADT();
            COMPUTE(0);
            if (t < 31) {
                WRITET(1);
                __syncthreads();
                kp += 64 * HDIM;
                vp += 64;
            }
        }
        {
            const int t = 2 * t2 + 1;
            if (t < 31) LOADT();
            COMPUTE(1);
            if (t < 31) {
                WRITET(0);
                __syncthreads();
                kp += 64 * HDIM;
                vp += 64;
            }
        }
    }

#undef LOADT
#undef WRITET
#undef COMPUTE

    // acc_l holds (in every register) the full P-sum for q-row lq:
    // normalize and write. No cross-lane reduce needed.
    const float inv = 1.0f / acc_l[0];
    unsigned short* cb = ctx + ((size_t)(b*SEQ + q0 + wv*16 + lq)) * EMBED + h*HDIM;
    #pragma unroll
    for (int i = 0; i < 4; ++i) {
        u32x2 ov;
        ov[0] = pack2(o[i][0] * inv, o[i][1] * inv);
        ov[1] = pack2(o[i][2] * inv, o[i][3] * inv);
        *(u32x2*)(cb + i*16 + lg*4) = ov;
    }
}

// ------------------------------------------------------------------
// Kernel 3: output projection (unchanged).
// ------------------------------------------------------------------
__global__ __launch_bounds__(256, 2) void out_proj(
    const unsigned short* __restrict__ ctx,
    const unsigned short* __restrict__ wob, const float* __restrict__ bo,
    float* __restrict__ out)
{
    const int m0 = blockIdx.x * 128;
    const int n0 = blockIdx.y * 128;

    __shared__ __align__(16) unsigned short a_lds[128 * 32];
    __shared__ __align__(16) unsigned short b_lds[128 * 32];

    const int tid  = threadIdx.x;
    const int lane = tid & 63;
    const int wid  = tid >> 6;
    const int wr   = wid >> 1, wc = wid & 1;
    const int lq   = lane & 15;
    const int lg   = lane >> 4;

    f32x4 acc[4][4] = {};

    const int srow  = wid * 32 + (lane >> 2);
    const int scol8 = (lane & 3) * 8;
    const unsigned short* ap0 = ctx + (size_t)(m0 + srow)      * EMBED + scol8;
    const unsigned short* ap1 = ctx + (size_t)(m0 + srow + 16) * EMBED + scol8;
    const unsigned short* bp0 = wob + (size_t)(n0 + srow)      * EMBED + scol8;
    const unsigned short* bp1 = wob + (size_t)(n0 + srow + 16) * EMBED + scol8;
    unsigned short* la0 = a_lds + wid * 1024;
    unsigned short* la1 = a_lds + wid * 1024 + 512;
    unsigned short* lb0 = b_lds + wid * 1024;
    unsigned short* lb1 = b_lds + wid * 1024 + 512;

    for (int k0 = 0; k0 < EMBED; k0 += 32) {
        glds16(ap0 + k0, la0);
        glds16(ap1 + k0, la1);
        glds16(bp0 + k0, lb0);
        glds16(bp1 + k0, lb1);
        __syncthreads();
        bf16x8 af[4], bfr[4];
        #pragma unroll
        for (int i = 0; i < 4; ++i)
            af[i] = *(const bf16x8*)&a_lds[(wr*64 + i*16 + lq) * 32 + lg*8];
        #pragma unroll
        for (int j = 0; j < 4; ++j)
            bfr[j] = *(const bf16x8*)&b_lds[(wc*64 + j*16 + lq) * 32 + lg*8];
        #pragma unroll
        for (int i = 0; i < 4; ++i)
            #pragma unroll
            for (int j = 0; j < 4; ++j)
                acc[i][j] = __builtin_amdgcn_mfma_f32_16x16x32_bf16(af[i], bfr[j], acc[i][j], 0, 0, 0);
        __syncthreads();
    }

    #pragma unroll
    for (int j = 0; j < 4; ++j) {
        const int nn = n0 + wc*64 + j*16 + lq;
        const float bsv = bo[nn];
        #pragma unroll
        for (int i = 0; i < 4; ++i) {
            const int mm = m0 + wr*64 + i*16 + lg*4;
            #pragma unroll
            for (int r = 0; r < 4; ++r)
                out[(size_t)(mm + r) * EMBED + nn] = acc[i][j][r] + bsv;
        }
    }
}

extern "C" void kernel_launch(void* const* d_in, const int* in_sizes, int n_in,
                              void* d_out, int out_size, void* d_ws, size_t ws_size,
                              hipStream_t stream) {
    const float* x  = (const float*)d_in[0];
    const float* wq = (const float*)d_in[1];
    const float* bq = (const float*)d_in[2];
    const float* wk = (const float*)d_in[3];
    const float* bk = (const float*)d_in[4];
    const float* wv = (const float*)d_in[5];
    const float* bv = (const float*)d_in[6];
    const float* wo = (const float*)d_in[7];
    const float* bo = (const float*)d_in[8];
    float* out = (float*)d_out;

    const size_t NELEM = (size_t)MTOT * EMBED;   // 4M elements
    const size_t WELEM = (size_t)EMBED * EMBED;  // 1M elements
    unsigned short* q_ws   = (unsigned short*)d_ws;
    unsigned short* k_ws   = q_ws  + NELEM;
    unsigned short* vt_ws  = k_ws  + NELEM;
    unsigned short* ctx_ws = vt_ws + NELEM;
    unsigned short* wqb    = ctx_ws + NELEM;
    unsigned short* wkb    = wqb + WELEM;
    unsigned short* wvb    = wkb + WELEM;
    unsigned short* wob    = wvb + WELEM;        // total 40 MB
    unsigned short* xb     = ctx_ws;             // alias: consumed before ctx written

    const int NCONV = (int)((NELEM + 4 * WELEM) / 4);
    preconvert<<<dim3(NCONV / 256), 256, 0, stream>>>(
        x, wq, wk, wv, wo, xb, wqb, wkb, wvb, wob);
    qkv_proj<<<dim3(MTOT/128, EMBED/128, 3), 256, 0, stream>>>(
        xb, wqb, bq, wkb, bk, wvb, bv, q_ws, k_ws, vt_ws);
    attn<<<dim3((SEQ/64) * BATCH*HEADS), 256, 0, stream>>>(q_ws, k_ws, vt_ws, ctx_ws);
    out_proj<<<dim3(MTOT/128, EMBED/128), 256, 0, stream>>>(ctx_ws, wob, bo, out);
}

// Round 20
// 125.364 us; speedup vs baseline: 1.0809x; 1.0809x over previous
//
#include <hip/hip_runtime.h>
#include <hip/hip_bf16.h>

#define EMBED 1024
#define HEADS 16
#define HDIM  64
#define BATCH 2
#define SEQ   2048
#define MTOT  (BATCH*SEQ)   // 4096

typedef __attribute__((ext_vector_type(8))) short bf16x8;
typedef __attribute__((ext_vector_type(4))) short bf16x4;
typedef __attribute__((ext_vector_type(4))) float f32x4;
typedef __attribute__((ext_vector_type(8))) unsigned short u16x8;
typedef __attribute__((ext_vector_type(2))) unsigned u32x2;
typedef __attribute__((ext_vector_type(4))) unsigned u32x4;

// native RNE f32->bf16 pair: compiles to one v_cvt_pk_bf16_f32
__device__ __forceinline__ unsigned pack2(float lo, float hi) {
    __hip_bfloat162 h = __float22bfloat162_rn(make_float2(lo, hi));
    unsigned u;
    __builtin_memcpy(&u, &h, sizeof(u));
    return u;
}
__device__ __forceinline__ unsigned short f2bf(float f) {
    __hip_bfloat16 h = __float2bfloat16(f);
    unsigned short u;
    __builtin_memcpy(&u, &h, sizeof(u));
    return u;
}

// async global->LDS DMA, 16B per lane (dest = lds base + lane*16)
__device__ __forceinline__ void glds16(const void* g, void* l) {
    __builtin_amdgcn_global_load_lds(
        (const __attribute__((address_space(1))) void*)g,
        (__attribute__((address_space(3))) void*)l, 16, 0, 0);
}

// ------------------------------------------------------------------
// Kernel 0: one-shot f32 -> bf16 conversion of x and the 4 weights.
// ------------------------------------------------------------------
__global__ __launch_bounds__(256) void preconvert(
    const float* __restrict__ x,
    const float* __restrict__ wq, const float* __restrict__ wk,
    const float* __restrict__ wv, const float* __restrict__ wo,
    unsigned short* __restrict__ xb,
    unsigned short* __restrict__ wqb, unsigned short* __restrict__ wkb,
    unsigned short* __restrict__ wvb, unsigned short* __restrict__ wob)
{
    const int NX = (MTOT * EMBED) / 4;
    const int NW = (EMBED * EMBED) / 4;
    int idx = blockIdx.x * 256 + threadIdx.x;
    const float* src;
    unsigned short* dst;
    int off;
    if (idx < NX) {
        src = x; dst = xb; off = idx;
    } else {
        int r = idx - NX;
        int w = r / NW;
        off = r - w * NW;
        src = (w == 0) ? wq : (w == 1) ? wk : (w == 2) ? wv : wo;
        dst = (w == 0) ? wqb : (w == 1) ? wkb : (w == 2) ? wvb : wob;
    }
    float4 v = ((const float4*)src)[off];
    u32x2 o;
    o[0] = pack2(v.x, v.y);
    o[1] = pack2(v.z, v.w);
    *(u32x2*)(dst + (size_t)off * 4) = o;
}

// ------------------------------------------------------------------
// Kernel 1: QKV projection (m97 glds staging; K pre-scaled by
// 0.125*log2e so attention scores come out in exp2 units).
// ------------------------------------------------------------------
__global__ __launch_bounds__(256, 2) void qkv_proj(
    const unsigned short* __restrict__ xb,
    const unsigned short* __restrict__ wqb, const float* __restrict__ bq,
    const unsigned short* __restrict__ wkb, const float* __restrict__ bk,
    const unsigned short* __restrict__ wvb, const float* __restrict__ bv,
    unsigned short* __restrict__ qo,
    unsigned short* __restrict__ ko,
    unsigned short* __restrict__ vto)
{
    const int which = blockIdx.z;
    const unsigned short* __restrict__ w =
        (which == 0) ? wqb : (which == 1) ? wkb : wvb;
    const float* __restrict__ bias = (which == 0) ? bq : (which == 1) ? bk : bv;
    const float kscale = (which == 1) ? 0.18033688f : 1.0f;  // 0.125*log2e

    const int m0 = blockIdx.x * 128;
    const int n0 = blockIdx.y * 128;

    __shared__ __align__(16) unsigned short a_lds[128 * 32];
    __shared__ __align__(16) unsigned short b_lds[128 * 32];

    const int tid  = threadIdx.x;
    const int lane = tid & 63;
    const int wid  = tid >> 6;
    const int wr   = wid >> 1, wc = wid & 1;
    const int lq   = lane & 15;
    const int lg   = lane >> 4;

    f32x4 acc[4][4] = {};

    const int srow  = wid * 32 + (lane >> 2);
    const int scol8 = (lane & 3) * 8;
    const unsigned short* ap0 = xb + (size_t)(m0 + srow)      * EMBED + scol8;
    const unsigned short* ap1 = xb + (size_t)(m0 + srow + 16) * EMBED + scol8;
    const unsigned short* bp0 = w  + (size_t)(n0 + srow)      * EMBED + scol8;
    const unsigned short* bp1 = w  + (size_t)(n0 + srow + 16) * EMBED + scol8;
    unsigned short* la0 = a_lds + wid * 1024;
    unsigned short* la1 = a_lds + wid * 1024 + 512;
    unsigned short* lb0 = b_lds + wid * 1024;
    unsigned short* lb1 = b_lds + wid * 1024 + 512;

    for (int k0 = 0; k0 < EMBED; k0 += 32) {
        glds16(ap0 + k0, la0);
        glds16(ap1 + k0, la1);
        glds16(bp0 + k0, lb0);
        glds16(bp1 + k0, lb1);
        __syncthreads();
        bf16x8 af[4], bfr[4];
        #pragma unroll
        for (int i = 0; i < 4; ++i)
            af[i] = *(const bf16x8*)&a_lds[(wr*64 + i*16 + lq) * 32 + lg*8];
        #pragma unroll
        for (int j = 0; j < 4; ++j)
            bfr[j] = *(const bf16x8*)&b_lds[(wc*64 + j*16 + lq) * 32 + lg*8];
        #pragma unroll
        for (int i = 0; i < 4; ++i)
            #pragma unroll
            for (int j = 0; j < 4; ++j)
                acc[i][j] = __builtin_amdgcn_mfma_f32_16x16x32_bf16(af[i], bfr[j], acc[i][j], 0, 0, 0);
        __syncthreads();
    }

    #pragma unroll
    for (int j = 0; j < 4; ++j) {
        const int nn = n0 + wc*64 + j*16 + lq;
        const float bsv = bias[nn];
        const int h = nn >> 6, d = nn & (HDIM-1);
        #pragma unroll
        for (int i = 0; i < 4; ++i) {
            const int mmb = m0 + wr*64 + i*16 + lg*4;
            const int b = mmb >> 11;
            const int s = mmb & (SEQ-1);
            const size_t bh = (size_t)(b*HEADS + h);
            if (which == 2) {
                u32x2 ov;
                ov[0] = pack2(acc[i][j][0] + bsv, acc[i][j][1] + bsv);
                ov[1] = pack2(acc[i][j][2] + bsv, acc[i][j][3] + bsv);
                *(u32x2*)&vto[(bh*HDIM + d)*SEQ + s] = ov;
            } else {
                unsigned short* o = (which == 0) ? qo : ko;
                #pragma unroll
                for (int r = 0; r < 4; ++r)
                    o[(bh*SEQ + (s + r))*HDIM + d] = f2bf((acc[i][j][r] + bsv) * kscale);
            }
        }
    }
}

// ------------------------------------------------------------------
// Kernel 2: flash attention (R18 config — best measured total: 512
// blocks, 4 waves, 32 q-rows/wave (2 q-frags), K-row-permuted QK^T,
// K=32 PV with lane-local P, zero-conflict row-hash LDS, ones-MFMA
// l-accum, no online max, T5 setprio around the PV MFMA cluster).
// ------------------------------------------------------------------
__global__ __launch_bounds__(256, 2) void attn(
    const unsigned short* __restrict__ q,
    const unsigned short* __restrict__ k,
    const unsigned short* __restrict__ vt,
    unsigned short* __restrict__ ctx)
{
    __shared__ __align__(16) unsigned char sm[2 * 16384];  // per buf: K 8KB, V 8KB

    const int bid   = blockIdx.x;          // 0..511
    const int xcd   = bid & 7;
    const int local = bid >> 3;            // 0..63
    const int bh    = xcd * 4 + (local >> 4);
    const int q0    = (local & 15) * 128;  // 128 q-rows per block
    const int b     = bh >> 4;
    const int h     = bh & (HEADS - 1);
    const int tid   = threadIdx.x;
    const int wv    = tid >> 6;
    const int lane  = tid & 63;
    const int lq = lane & 15, lg = lane >> 4;

    const unsigned short* qb = q  + (size_t)bh * SEQ * HDIM;
    const unsigned short* kb = k  + (size_t)bh * SEQ * HDIM;
    const unsigned short* vb = vt + (size_t)bh * HDIM * SEQ;

    // K-read offsets: row perm(sub,lq) with lane-constant swizzle
    const int lg16 = lg * 16;
    const int Sp = (((lq & 3) | (((lq >> 2) & 1) << 2)) << 4);
    const int Tp = (((lq & 3) | (((lq >> 3) & 1) << 2)) << 4);
    const int kreadA = (8*(lq >> 2) + (lq & 3)) * 128 + (lg16 ^ Sp);  // d 0-31
    const int kreadB = kreadA ^ 64;                                    // d 32-63
    const int vreadA = lq * 128 + (lg16 ^ Tp);   // + i*2048, kv 0-31
    const int vreadB = vreadA ^ 64;              //            kv 32-63

    // staging offsets (identical for K and V tiles)
    const int wrow = tid >> 3;             // 0..31
    const int c8   = tid & 7;              // 0..7
    const int wS   = (((wrow & 3) | (((wrow >> 3) & 1) << 2)) << 4);
    const int woff = wrow * 128 + ((c8 * 16) ^ wS);

    const int scol = c8 * 8;
    const unsigned short* kp = kb + (size_t)wrow * HDIM + scol;
    const unsigned short* vp = vb + (size_t)wrow * SEQ + scol;

    // this wave's 32 q-rows: frag t at rows q0 + wv*32 + t*16 + lq
    bf16x8 qf[2][2];
    #pragma unroll
    for (int t = 0; t < 2; ++t)
        #pragma unroll
        for (int hh = 0; hh < 2; ++hh)
            qf[t][hh] = *(const bf16x8*)(qb + (size_t)(q0 + wv*32 + t*16 + lq) * HDIM + hh*32 + lg*8);

    // ones fragment (bf16 1.0 = 0x3F80) for the P-sum MFMA
    u16x8 ones_u;
    #pragma unroll
    for (int e = 0; e < 8; ++e) ones_u[e] = 0x3F80;
    const bf16x8 ones = __builtin_bit_cast(bf16x8, ones_u);

    f32x4 o[2][4] = {};
    f32x4 acc_l[2] = {};

    u16x8 kr0, kr1, vr0, vr1;

#define LOADT() do {                                                           \
    kr0 = *(const u16x8*)(kp);                                                 \
    kr1 = *(const u16x8*)(kp + 32*HDIM);                                       \
    vr0 = *(const u16x8*)(vp);                                                 \
    vr1 = *(const u16x8*)(vp + 32*SEQ);                                        \
} while (0)

#define WRITET(BF) do {                                                        \
    unsigned char* smb = sm + (BF)*16384;                                      \
    *(u16x8*)(smb +         woff) = kr0;                                       \
    *(u16x8*)(smb +  4096 + woff) = kr1;                                       \
    *(u16x8*)(smb +  8192 + woff) = vr0;                                       \
    *(u16x8*)(smb + 12288 + woff) = vr1;                                       \
} while (0)

#define COMPUTE(BF) do {                                                       \
    const unsigned char* smb = sm + (BF)*16384;                                \
    f32x4 s_[2][4];                                                            \
    _Pragma("unroll")                                                          \
    for (int sub = 0; sub < 4; ++sub) {                                        \
        const int sadd = (sub & 1) * 512 + (sub >> 1) * 4096;                  \
        bf16x8 k0 = *(const bf16x8*)(smb + sadd + kreadA);                     \
        bf16x8 k1 = *(const bf16x8*)(smb + sadd + kreadB);                     \
        _Pragma("unroll")                                                      \
        for (int t = 0; t < 2; ++t) {                                          \
            f32x4 z = {};                                                      \
            z = __builtin_amdgcn_mfma_f32_16x16x32_bf16(k0, qf[t][0], z, 0, 0, 0); \
            z = __builtin_amdgcn_mfma_f32_16x16x32_bf16(k1, qf[t][1], z, 0, 0, 0); \
            s_[t][sub] = z;                                                    \
        }                                                                      \
    }                                                                          \
    bf16x8 pb[2][2];                                                           \
    _Pragma("unroll")                                                          \
    for (int t = 0; t < 2; ++t) {                                              \
        u32x4 pw0, pw1;                                                        \
        _Pragma("unroll")                                                      \
        for (int sub = 0; sub < 4; ++sub) {                                    \
            f32x4 pv;                                                          \
            _Pragma("unroll")                                                  \
            for (int r = 0; r < 4; ++r) pv[r] = exp2f(s_[t][sub][r]);          \
            unsigned d0 = pack2(pv[0], pv[1]);                                 \
            unsigned d1 = pack2(pv[2], pv[3]);                                 \
            if (sub == 0)      { pw0[0] = d0; pw0[1] = d1; }                   \
            else if (sub == 1) { pw0[2] = d0; pw0[3] = d1; }                   \
            else if (sub == 2) { pw1[0] = d0; pw1[1] = d1; }                   \
            else               { pw1[2] = d0; pw1[3] = d1; }                   \
        }                                                                      \
        pb[t][0] = __builtin_bit_cast(bf16x8, pw0);                            \
        pb[t][1] = __builtin_bit_cast(bf16x8, pw1);                            \
        acc_l[t] = __builtin_amdgcn_mfma_f32_16x16x32_bf16(ones, pb[t][0], acc_l[t], 0, 0, 0); \
        acc_l[t] = __builtin_amdgcn_mfma_f32_16x16x32_bf16(ones, pb[t][1], acc_l[t], 0, 0, 0); \
    }                                                                          \
    __builtin_amdgcn_s_setprio(1);                                             \
    _Pragma("unroll")                                                          \
    for (int i = 0; i < 4; ++i) {                                              \
        bf16x8 va  = *(const bf16x8*)(smb + 8192 + i*2048 + vreadA);           \
        bf16x8 vbq = *(const bf16x8*)(smb + 8192 + i*2048 + vreadB);           \
        _Pragma("unroll")                                                      \
        for (int t = 0; t < 2; ++t) {                                          \
            o[t][i] = __builtin_amdgcn_mfma_f32_16x16x32_bf16(va,  pb[t][0], o[t][i], 0, 0, 0); \
            o[t][i] = __builtin_amdgcn_mfma_f32_16x16x32_bf16(vbq, pb[t][1], o[t][i], 0, 0, 0); \
        }                                                                      \
    }                                                                          \
    __builtin_amdgcn_s_setprio(0);                                             \
} while (0)

    LOADT();
    WRITET(0);
    __syncthreads();
    kp += 64 * HDIM;
    vp += 64;

    for (int t2 = 0; t2 < 16; ++t2) {
        {
            const int t = 2 * t2;
            if (t < 31) LOADT();
            COMPUTE(0);
            if (t < 31) {
                WRITET(1);
                __syncthreads();
                kp += 64 * HDIM;
                vp += 64;
            }
        }
        {
            const int t = 2 * t2 + 1;
            if (t < 31) LOADT();
            COMPUTE(1);
            if (t < 31) {
                WRITET(0);
                __syncthreads();
                kp += 64 * HDIM;
                vp += 64;
            }
        }
    }

#undef LOADT
#undef WRITET
#undef COMPUTE

    // acc_l[t] holds (in every register) the full P-sum for q-row lq:
    // normalize and write. No cross-lane reduce needed.
    #pragma unroll
    for (int t = 0; t < 2; ++t) {
        const float inv = 1.0f / acc_l[t][0];
        unsigned short* cb = ctx + ((size_t)(b*SEQ + q0 + wv*32 + t*16 + lq)) * EMBED + h*HDIM;
        #pragma unroll
        for (int i = 0; i < 4; ++i) {
            u32x2 ov;
            ov[0] = pack2(o[t][i][0] * inv, o[t][i][1] * inv);
            ov[1] = pack2(o[t][i][2] * inv, o[t][i][3] * inv);
            *(u32x2*)(cb + i*16 + lg*4) = ov;
        }
    }
}

// ------------------------------------------------------------------
// Kernel 3: output projection (m97 glds staging).
// ------------------------------------------------------------------
__global__ __launch_bounds__(256, 2) void out_proj(
    const unsigned short* __restrict__ ctx,
    const unsigned short* __restrict__ wob, const float* __restrict__ bo,
    float* __restrict__ out)
{
    const int m0 = blockIdx.x * 128;
    const int n0 = blockIdx.y * 128;

    __shared__ __align__(16) unsigned short a_lds[128 * 32];
    __shared__ __align__(16) unsigned short b_lds[128 * 32];

    const int tid  = threadIdx.x;
    const int lane = tid & 63;
    const int wid  = tid >> 6;
    const int wr   = wid >> 1, wc = wid & 1;
    const int lq   = lane & 15;
    const int lg   = lane >> 4;

    f32x4 acc[4][4] = {};

    const int srow  = wid * 32 + (lane >> 2);
    const int scol8 = (lane & 3) * 8;
    const unsigned short* ap0 = ctx + (size_t)(m0 + srow)      * EMBED + scol8;
    const unsigned short* ap1 = ctx + (size_t)(m0 + srow + 16) * EMBED + scol8;
    const unsigned short* bp0 = wob + (size_t)(n0 + srow)      * EMBED + scol8;
    const unsigned short* bp1 = wob + (size_t)(n0 + srow + 16) * EMBED + scol8;
    unsigned short* la0 = a_lds + wid * 1024;
    unsigned short* la1 = a_lds + wid * 1024 + 512;
    unsigned short* lb0 = b_lds + wid * 1024;
    unsigned short* lb1 = b_lds + wid * 1024 + 512;

    for (int k0 = 0; k0 < EMBED; k0 += 32) {
        glds16(ap0 + k0, la0);
        glds16(ap1 + k0, la1);
        glds16(bp0 + k0, lb0);
        glds16(bp1 + k0, lb1);
        __syncthreads();
        bf16x8 af[4], bfr[4];
        #pragma unroll
        for (int i = 0; i < 4; ++i)
            af[i] = *(const bf16x8*)&a_lds[(wr*64 + i*16 + lq) * 32 + lg*8];
        #pragma unroll
        for (int j = 0; j < 4; ++j)
            bfr[j] = *(const bf16x8*)&b_lds[(wc*64 + j*16 + lq) * 32 + lg*8];
        #pragma unroll
        for (int i = 0; i < 4; ++i)
            #pragma unroll
            for (int j = 0; j < 4; ++j)
                acc[i][j] = __builtin_amdgcn_mfma_f32_16x16x32_bf16(af[i], bfr[j], acc[i][j], 0, 0, 0);
        __syncthreads();
    }

    #pragma unroll
    for (int j = 0; j < 4; ++j) {
        const int nn = n0 + wc*64 + j*16 + lq;
        const float bsv = bo[nn];
        #pragma unroll
        for (int i = 0; i < 4; ++i) {
            const int mm = m0 + wr*64 + i*16 + lg*4;
            #pragma unroll
            for (int r = 0; r < 4; ++r)
                out[(size_t)(mm + r) * EMBED + nn] = acc[i][j][r] + bsv;
        }
    }
}

extern "C" void kernel_launch(void* const* d_in, const int* in_sizes, int n_in,
                              void* d_out, int out_size, void* d_ws, size_t ws_size,
                              hipStream_t stream) {
    const float* x  = (const float*)d_in[0];
    const float* wq = (const float*)d_in[1];
    const float* bq = (const float*)d_in[2];
    const float* wk = (const float*)d_in[3];
    const float* bk = (const float*)d_in[4];
    const float* wv = (const float*)d_in[5];
    const float* bv = (const float*)d_in[6];
    const float* wo = (const float*)d_in[7];
    const float* bo = (const float*)d_in[8];
    float* out = (float*)d_out;

    const size_t NELEM = (size_t)MTOT * EMBED;   // 4M elements
    const size_t WELEM = (size_t)EMBED * EMBED;  // 1M elements
    unsigned short* q_ws   = (unsigned short*)d_ws;
    unsigned short* k_ws   = q_ws  + NELEM;
    unsigned short* vt_ws  = k_ws  + NELEM;
    unsigned short* ctx_ws = vt_ws + NELEM;
    unsigned short* wqb    = ctx_ws + NELEM;
    unsigned short* wkb    = wqb + WELEM;
    unsigned short* wvb    = wkb + WELEM;
    unsigned short* wob    = wvb + WELEM;        // total 40 MB
    unsigned short* xb     = ctx_ws;             // alias: consumed before ctx written

    const int NCONV = (int)((NELEM + 4 * WELEM) / 4);
    preconvert<<<dim3(NCONV / 256), 256, 0, stream>>>(
        x, wq, wk, wv, wo, xb, wqb, wkb, wvb, wob);
    qkv_proj<<<dim3(MTOT/128, EMBED/128, 3), 256, 0, stream>>>(
        xb, wqb, bq, wkb, bk, wvb, bv, q_ws, k_ws, vt_ws);
    attn<<<dim3((SEQ/128) * BATCH*HEADS), 256, 0, stream>>>(q_ws, k_ws, vt_ws, ctx_ws);
    out_proj<<<dim3(MTOT/128, EMBED/128), 256, 0, stream>>>(ctx_ws, wob, bo, out);
}